// Round 1
// 240.989 us; speedup vs baseline: 1.0357x; 1.0357x over previous
//
#include <hip/hip_runtime.h>

// out[r, i] = sum_{k=0..4} W[i,k] * x[r, i+k-2] + b[i], zero-padded at edges.
// B=8192 rows, C=4096 channels, K=5, fp32.
//
// R1: per-(row,channel) W loads made the kernel L1/TA line-request bound.
// R2: thread owns 4 channels, W+bias in registers, loops rows. 91 us/dispatch.
// R3 (this): counters showed Occupancy=56% (grid==residency, no backfill ->
// finish-variance tail) and FETCH=69MB (out stores evict x from the 256MB L3;
// x+out=268MB). Fixes:
//   - ROWS_PER_BLOCK 16->8: 4096 blocks = 16/CU -> one backfill round absorbs
//     per-block finish variance.
//   - nontemporal stores for out (write-once data, keep x L3-resident).
//   - explicit distance-1 prefetch pipeline, full unroll: >=6 loads in flight
//     before any wait; __launch_bounds__(256,8) pins <=64 VGPR (8 waves/SIMD).

#define B_ROWS 8192
#define C_CH   4096
#define KWIN   5
#define ROWS_PER_BLOCK 8

typedef float vf4 __attribute__((ext_vector_type(4)));

__global__ __launch_bounds__(256, 8) void grouped_linear_kernel(
    const float* __restrict__ x, const float* __restrict__ W,
    const float* __restrict__ bias, float* __restrict__ out)
{
    // chunk = which group of 4 channels this thread owns (0..1023)
    const int chunk = (blockIdx.x << 8) + threadIdx.x;   // gridDim.x == 4
    const int c     = chunk << 2;                        // base channel
    const int r0    = blockIdx.y * ROWS_PER_BLOCK;

    // --- loop-invariant: W rows c..c+3 (20 contiguous floats) + bias ---
    const float4* W4 = (const float4*)(W + (size_t)c * KWIN);
    const float4 w0 = W4[0];  // W[c][0..3]
    const float4 w1 = W4[1];  // W[c][4], W[c+1][0..2]
    const float4 w2 = W4[2];  // W[c+1][3..4], W[c+2][0..1]
    const float4 w3 = W4[3];  // W[c+2][2..4], W[c+3][0]
    const float4 w4 = W4[4];  // W[c+3][1..4]
    const float4 bv = ((const float4*)bias)[chunk];

    const bool has_m = (c > 0);
    const bool has_p = (c + 4 < C_CH);
    const float4 zero = make_float4(0.f, 0.f, 0.f, 0.f);

    const float4* xrow = (const float4*)(x   + (size_t)r0 * C_CH);
    float4*       orow = (float4*)      (out + (size_t)r0 * C_CH);
    const int rstride = C_CH / 4;

    // software pipeline, distance 1: loads for row r+1 issue before row r's
    // compute+store, so the wave always has the next row's 3 loads in flight.
    float4 xm = has_m ? xrow[chunk - 1] : zero;
    float4 xc = xrow[chunk];
    float4 xp = has_p ? xrow[chunk + 1] : zero;

    #pragma unroll
    for (int r = 0; r < ROWS_PER_BLOCK; ++r) {
        float4 nm = zero, nc = zero, np = zero;
        if (r + 1 < ROWS_PER_BLOCK) {
            const float4* nx = xrow + rstride;
            nm = has_m ? nx[chunk - 1] : zero;
            nc = nx[chunk];
            np = has_p ? nx[chunk + 1] : zero;
        }

        // win[m] = x[r, c - 2 + m], m = 0..7
        const float win0 = xm.z, win1 = xm.w;
        const float win2 = xc.x, win3 = xc.y, win4 = xc.z, win5 = xc.w;
        const float win6 = xp.x, win7 = xp.y;

        float4 o;
        o.x = fmaf(w0.x, win0, fmaf(w0.y, win1, fmaf(w0.z, win2, fmaf(w0.w, win3, fmaf(w1.x, win4, bv.x)))));
        o.y = fmaf(w1.y, win1, fmaf(w1.z, win2, fmaf(w1.w, win3, fmaf(w2.x, win4, fmaf(w2.y, win5, bv.y)))));
        o.z = fmaf(w2.z, win2, fmaf(w2.w, win3, fmaf(w3.x, win4, fmaf(w3.y, win5, fmaf(w3.z, win6, bv.z)))));
        o.w = fmaf(w3.w, win3, fmaf(w4.x, win4, fmaf(w4.y, win5, fmaf(w4.z, win6, fmaf(w4.w, win7, bv.w)))));

        // out is write-once, never re-read: stream past L2/L3 so x stays
        // L3-resident across dispatches (FETCH_SIZE was 69MB of x re-fetch).
        vf4 ov; ov.x = o.x; ov.y = o.y; ov.z = o.z; ov.w = o.w;
        __builtin_nontemporal_store(ov, (vf4*)(orow + chunk));

        xm = nm; xc = nc; xp = np;
        xrow += rstride;
        orow += rstride;
    }
}

extern "C" void kernel_launch(void* const* d_in, const int* in_sizes, int n_in,
                              void* d_out, int out_size, void* d_ws, size_t ws_size,
                              hipStream_t stream) {
    const float* x    = (const float*)d_in[0];
    const float* W    = (const float*)d_in[1];
    const float* bias = (const float*)d_in[2];
    float* out = (float*)d_out;

    dim3 grid(C_CH / 4 / 256, B_ROWS / ROWS_PER_BLOCK);  // (4, 1024) = 4096 blocks
    dim3 block(256);
    grouped_linear_kernel<<<grid, block, 0, stream>>>(x, W, bias, out);
}

// Round 2
// 237.788 us; speedup vs baseline: 1.0496x; 1.0135x over previous
//
#include <hip/hip_runtime.h>

// out[r, i] = sum_{k=0..4} W[i,k] * x[r, i+k-2] + b[i], zero-padded at edges.
// B=8192 rows, C=4096 channels, K=5, fp32.
//
// R1: per-(row,channel) W loads -> L1/TA line-request bound.
// R2: thread owns 4 channels, W+bias in regs, loops rows. 91 us/dispatch.
// R3: 4096 blocks (16/CU backfill) fixed occupancy 56->67%; 83 us. nt stores
//     FAILED: +12.5% WRITE_SIZE, FETCH unchanged (harness memset of out evicts
//     x from L3, not our stores) -> reverted here.
// R4 (this): counters showed waves stall ~12K cyc/row (VALUBusy 6%) with the
// request path saturated at 2.6 TB/s << 6.3 achievable. Cause: 3 overlapping
// halo loads per row = ~51 L1 lines for 16 unique. Fix: each thread loads ONLY
// its own float4; halo comes from adjacent lanes via __shfl_up/down. Lanes
// 0/63 of each wave fetch the real cross-wave halo with ONE exec-masked load
// (2 active lanes). Per wave-row: 4 VMEM insts/~67 lines -> 3 insts/~34 lines.

#define B_ROWS 8192
#define C_CH   4096
#define KWIN   5
#define ROWS_PER_BLOCK 8
#define NCHUNK (C_CH / 4)   // 1024 float4 chunks per row

__global__ __launch_bounds__(256, 8) void grouped_linear_kernel(
    const float* __restrict__ x, const float* __restrict__ W,
    const float* __restrict__ bias, float* __restrict__ out)
{
    // chunk = which group of 4 channels this thread owns (0..1023)
    const int chunk = (blockIdx.x << 8) + threadIdx.x;   // gridDim.x == 4
    const int c     = chunk << 2;                        // base channel
    const int r0    = blockIdx.y * ROWS_PER_BLOCK;
    const int lane  = threadIdx.x & 63;

    // --- loop-invariant: W rows c..c+3 (20 contiguous floats) + bias ---
    const float4* W4 = (const float4*)(W + (size_t)c * KWIN);
    const float4 w0 = W4[0];  // W[c][0..3]
    const float4 w1 = W4[1];  // W[c][4], W[c+1][0..2]
    const float4 w2 = W4[2];  // W[c+1][3..4], W[c+2][0..1]
    const float4 w3 = W4[3];  // W[c+2][2..4], W[c+3][0]
    const float4 w4 = W4[4];  // W[c+3][1..4]
    const float4 bv = ((const float4*)bias)[chunk];

    const float4 zero = make_float4(0.f, 0.f, 0.f, 0.f);

    // Halo: only wave-edge lanes touch memory for it. Lane 0 needs chunk-1
    // (uses .z,.w), lane 63 needs chunk+1 (uses .x,.y). One masked load.
    const bool is_lo = (lane == 0);
    const bool is_hi = (lane == 63);
    const int  hchunk = is_lo ? (chunk - 1) : (chunk + 1);
    const bool hvalid = (is_lo && chunk > 0) || (is_hi && chunk + 1 < NCHUNK);

    const float4* xrow = (const float4*)(x   + (size_t)r0 * C_CH);
    float4*       orow = (float4*)      (out + (size_t)r0 * C_CH);
    const int rstride = C_CH / 4;

    // software pipeline, distance 1
    float4 xc = xrow[chunk];
    float4 hl = zero;
    if (hvalid) hl = xrow[hchunk];

    #pragma unroll
    for (int r = 0; r < ROWS_PER_BLOCK; ++r) {
        float4 nc = zero, nh = zero;
        if (r + 1 < ROWS_PER_BLOCK) {
            const float4* nx = xrow + rstride;
            nc = nx[chunk];
            if (hvalid) nh = nx[hchunk];
        }

        // halo via cross-lane: left neighbor's .z/.w, right neighbor's .x/.y
        float mz = __shfl_up(xc.z, 1);
        float mw = __shfl_up(xc.w, 1);
        float px = __shfl_down(xc.x, 1);
        float py = __shfl_down(xc.y, 1);

        // win[m] = x[r, c - 2 + m], m = 0..7
        const float win0 = is_lo ? hl.z : mz;
        const float win1 = is_lo ? hl.w : mw;
        const float win2 = xc.x, win3 = xc.y, win4 = xc.z, win5 = xc.w;
        const float win6 = is_hi ? hl.x : px;
        const float win7 = is_hi ? hl.y : py;

        float4 o;
        o.x = fmaf(w0.x, win0, fmaf(w0.y, win1, fmaf(w0.z, win2, fmaf(w0.w, win3, fmaf(w1.x, win4, bv.x)))));
        o.y = fmaf(w1.y, win1, fmaf(w1.z, win2, fmaf(w1.w, win3, fmaf(w2.x, win4, fmaf(w2.y, win5, bv.y)))));
        o.z = fmaf(w2.z, win2, fmaf(w2.w, win3, fmaf(w3.x, win4, fmaf(w3.y, win5, fmaf(w3.z, win6, bv.z)))));
        o.w = fmaf(w3.w, win3, fmaf(w4.x, win4, fmaf(w4.y, win5, fmaf(w4.z, win6, fmaf(w4.w, win7, bv.w)))));

        orow[chunk] = o;

        xc = nc; hl = nh;
        xrow += rstride;
        orow += rstride;
    }
}

extern "C" void kernel_launch(void* const* d_in, const int* in_sizes, int n_in,
                              void* d_out, int out_size, void* d_ws, size_t ws_size,
                              hipStream_t stream) {
    const float* x    = (const float*)d_in[0];
    const float* W    = (const float*)d_in[1];
    const float* bias = (const float*)d_in[2];
    float* out = (float*)d_out;

    dim3 grid(C_CH / 4 / 256, B_ROWS / ROWS_PER_BLOCK);  // (4, 1024) = 4096 blocks
    dim3 block(256);
    grouped_linear_kernel<<<grid, block, 0, stream>>>(x, W, bias, out);
}